// Round 4
// baseline (365.989 us; speedup 1.0000x reference)
//
#include <hip/hip_runtime.h>

#define FDIM 128

typedef __attribute__((ext_vector_type(8))) short bf16x8;
typedef __attribute__((ext_vector_type(4))) float f32x4;

// Column permutation for internal Z/S/H storage (within a 128-col half):
//   orig c: ct=c>>4, n=c&15  ->  stored s = 64*(ct>=4) + n*4 + (ct&3)
//   inv:    hi=s>>6, s6=s&63, n=s6>>2, ctl=s6&3 -> c = (ctl+4*hi)*16 + n
// This makes each lane's 4 ctl accumulators contiguous in storage (8B packed
// stores in the GEMM epilogue, dwordx2 gathers in aggregate).

__device__ __forceinline__ unsigned short f2bf(float f){
  unsigned int u = __float_as_uint(f);
  unsigned int r = u + 0x7FFFu + ((u >> 16) & 1u);
  return (unsigned short)(r >> 16);
}

// ---------------- CSR build (padded to multiple of 8 per row) ----------------
__global__ void k_degree(const int* __restrict__ dst, int* __restrict__ cnt, int E){
  int e = blockIdx.x*256 + threadIdx.x;
  if (e < E) atomicAdd(&cnt[dst[e]], 1);
}

__global__ void k_scan_blocks(const int* __restrict__ cnt, int* __restrict__ excl,
                              int* __restrict__ partials, int N){
  __shared__ int s[256];
  int tid = threadIdx.x;
  int i = blockIdx.x*256 + tid;
  int v = (i < N) ? ((cnt[i] + 7) & ~7) : 0;   // scan PADDED degrees
  s[tid] = v; __syncthreads();
  for (int off = 1; off < 256; off <<= 1){
    int t = (tid >= off) ? s[tid - off] : 0;
    __syncthreads();
    s[tid] += t;
    __syncthreads();
  }
  if (i < N) excl[i] = s[tid] - v;
  if (tid == 255) partials[blockIdx.x] = s[255];
}

__global__ void k_scan_partials(int* __restrict__ partials, int nb){
  __shared__ int s[512];
  int tid = threadIdx.x;
  int v = (tid < nb) ? partials[tid] : 0;
  s[tid] = v; __syncthreads();
  for (int off = 1; off < 512; off <<= 1){
    int t = (tid >= off) ? s[tid - off] : 0;
    __syncthreads();
    s[tid] += t;
    __syncthreads();
  }
  if (tid < nb) partials[tid] = s[tid] - v;
}

__global__ void k_finalize(int* __restrict__ row_off, const int* __restrict__ partials,
                           int* __restrict__ cursor, int N){
  int i = blockIdx.x*256 + threadIdx.x;
  if (i >= N) return;
  int ro = row_off[i] + partials[blockIdx.x];
  row_off[i] = ro;
  cursor[i]  = ro;
}

__global__ void k_fill(const int* __restrict__ src, const int* __restrict__ dst,
                       int* __restrict__ cursor, int* __restrict__ csr_src, int E){
  int e = blockIdx.x*256 + threadIdx.x;
  if (e >= E) return;
  int d = dst[e];
  int pos = atomicAdd(&cursor[d], 1);
  csr_src[pos] = src[e];
}

// fill padding slots with dummy node index N (Z row N is zeroed)
__global__ void k_pad(const int* __restrict__ cnt, const int* __restrict__ row_off,
                      int* __restrict__ csr_src, int N){
  int i = blockIdx.x*256 + threadIdx.x;
  if (i >= N) return;
  int d  = cnt[i];
  int pd = (d + 7) & ~7;
  int ro = row_off[i];
  for (int p = d; p < pd; p++) csr_src[ro + p] = N;
}

// ---------------- weight pre-convert: Wcat[layer][256][128] bf16 ----------------
// Layer-2 weights get inverse-permuted k (their A input, H, is stored permuted).
__global__ void k_wcat(const float* __restrict__ Wl0, const float* __restrict__ Wr0,
                       const float* __restrict__ Wl1, const float* __restrict__ Wr1,
                       unsigned short* __restrict__ Wcat){
  int i = blockIdx.x*256 + threadIdx.x;
  if (i >= 2*256*128) return;
  int l   = i >> 15;
  int rem = i & 32767;
  int row = rem >> 7, k = rem & 127;
  int ksrc = k;
  if (l == 1){
    int hi = k >> 6, s6 = k & 63;
    ksrc = ((s6 & 3) + 4*hi)*16 + (s6 >> 2);   // invπ(k)
  }
  const float* W = (l == 0) ? ((row < 128) ? Wl0 : Wr0)
                            : ((row < 128) ? Wl1 : Wr1);
  Wcat[i] = f2bf(W[(row & 127)*128 + ksrc]);
}

// ---------------- dual GEMM: Z = X@Wl^T, S = X@Wr^T + (bl+br), permuted cols ----------------
template<bool A_BF16>
__global__ __launch_bounds__(256, 4)
void k_dualgemm(const void* __restrict__ Xv, const unsigned short* __restrict__ Wcat,
                const float* __restrict__ bl, const float* __restrict__ br,
                unsigned short* __restrict__ Z, unsigned short* __restrict__ S,
                int N, int nrb){
  __shared__ unsigned short lds[64*FDIM]; // 16 KiB
  const int tid  = threadIdx.x;
  const int wave = tid >> 6;
  const int lane = tid & 63;
  const int n = lane & 15, q = lane >> 4;

  float bias[4];
#pragma unroll
  for (int ctl = 0; ctl < 4; ctl++){
    int ct = wave*4 + ctl;
    if (ct >= 8){ int col = (ct - 8)*16 + n; bias[ctl] = bl[col] + br[col]; }
    else bias[ctl] = 0.0f;
  }

  for (int rb = blockIdx.x; rb < nrb; rb += gridDim.x){
    int row0 = rb*64;
    __syncthreads();
#pragma unroll
    for (int it = 0; it < 4; it++){
      int cu  = tid + it*256;
      int r   = cu >> 4, c16 = cu & 15;
      int gr  = row0 + r;
      bf16x8 p;
      if (gr < N){
        if constexpr (A_BF16){
          const unsigned short* X = (const unsigned short*)Xv;
          p = *(const bf16x8*)(X + (size_t)gr*FDIM + c16*8);
        } else {
          const float* X = (const float*)Xv;
          const float4* sp = (const float4*)(X + (size_t)gr*FDIM + c16*8);
          float4 v0 = sp[0], v1 = sp[1];
          p[0] = (short)f2bf(v0.x); p[1] = (short)f2bf(v0.y);
          p[2] = (short)f2bf(v0.z); p[3] = (short)f2bf(v0.w);
          p[4] = (short)f2bf(v1.x); p[5] = (short)f2bf(v1.y);
          p[6] = (short)f2bf(v1.z); p[7] = (short)f2bf(v1.w);
        }
      } else {
#pragma unroll
        for (int z = 0; z < 8; z++) p[z] = 0;
      }
      *(bf16x8*)(lds + r*FDIM + ((c16 ^ (r & 15)) * 8)) = p;
    }
    __syncthreads();

    f32x4 acc[4][4];
#pragma unroll
    for (int rt = 0; rt < 4; rt++)
#pragma unroll
      for (int ctl = 0; ctl < 4; ctl++)
        acc[rt][ctl] = (f32x4){0.f, 0.f, 0.f, 0.f};

#pragma unroll
    for (int kk = 0; kk < 4; kk++){
      bf16x8 bfr[4];
#pragma unroll
      for (int ctl = 0; ctl < 4; ctl++){
        int row = (wave*4 + ctl)*16 + n;
        bfr[ctl] = *(const bf16x8*)(Wcat + row*FDIM + kk*32 + q*8);
      }
      bf16x8 afr[4];
#pragma unroll
      for (int rt = 0; rt < 4; rt++){
        int r = rt*16 + n;
        int c16 = (kk*4 + q) ^ n;
        afr[rt] = *(const bf16x8*)(lds + r*FDIM + c16*8);
      }
#pragma unroll
      for (int rt = 0; rt < 4; rt++)
#pragma unroll
        for (int ctl = 0; ctl < 4; ctl++)
          acc[rt][ctl] = __builtin_amdgcn_mfma_f32_16x16x32_bf16(
              afr[rt], bfr[ctl], acc[rt][ctl], 0, 0, 0);
    }

    // epilogue: wave<2 -> Z half, wave>=2 -> S half.
    // stored cols for this lane: s0..s0+3 (ctl 0..3), s0 = 64*(wave&1) + n*4
    unsigned short* dstb = (wave < 2) ? Z : S;
    int s0 = 64*(wave & 1) + n*4;
#pragma unroll
    for (int rt = 0; rt < 4; rt++){
#pragma unroll
      for (int r = 0; r < 4; r++){
        int grow = row0 + rt*16 + q*4 + r;
        if (grow < N){
          float v0 = acc[rt][0][r] + bias[0];
          float v1 = acc[rt][1][r] + bias[1];
          float v2 = acc[rt][2][r] + bias[2];
          float v3 = acc[rt][3][r] + bias[3];
          uint2 u;
          u.x = ((unsigned)f2bf(v1) << 16) | (unsigned)f2bf(v0);
          u.y = ((unsigned)f2bf(v3) << 16) | (unsigned)f2bf(v2);
          *(uint2*)(dstb + (size_t)grow*FDIM + s0) = u;
        }
      }
    }
  }
}

// ---------------- aggregate + finish: out = relu(sum(Z[src])/deg + S) ----------------
// One wave per node. Padded CSR (multiple of 8, dummy -> zero row N of Z).
// dwordx2 gathers: lanes 0-31 cover one row (4 stored cols/lane), lanes 32-63
// the next edge's row; xor-32 combine at the end. No masks in the inner loop.
template<bool OUT_BF16>
__global__ __launch_bounds__(256)
void k_aggregate(const unsigned short* __restrict__ Z, const unsigned short* __restrict__ S,
                 const int* __restrict__ row_off, const int* __restrict__ cnt,
                 const int* __restrict__ csr_src, void* __restrict__ OutV, int N){
  int wave = threadIdx.x >> 6, lane = threadIdx.x & 63;
  int node = blockIdx.x*4 + wave;
  if (node >= N) return;
  int start = row_off[node];
  int deg   = cnt[node];
  int pdeg  = (deg + 7) & ~7;
  float inv = 1.0f / (float)(deg > 1 ? deg : 1);
  int L = lane & 31, half = lane >> 5;
  uint2 sv = *(const uint2*)(S + (size_t)node*FDIM + L*4);

  const int* cb = csr_src + start;
  float a0 = 0.f, a1 = 0.f, a2 = 0.f, a3 = 0.f;
  for (int base = 0; base < pdeg; base += 64){
    int m = pdeg - base; if (m > 64) m = 64;      // multiple of 8
    int sidx = (lane < m) ? cb[base + lane] : N;
    for (int j = 0; j < m; j += 8){
      int id[4];
#pragma unroll
      for (int t = 0; t < 4; t++)
        id[t] = __shfl(sidx, j + 2*t + half);     // 4 bpermutes / 8 edges
      uint2 v[4];
#pragma unroll
      for (int t = 0; t < 4; t++){
        unsigned u = (unsigned)id[t];
        if (u > (unsigned)N) u = (unsigned)N;     // defensive clamp (row N = zeros)
        v[t] = *(const uint2*)(Z + (size_t)u*FDIM + L*4);
      }
#pragma unroll
      for (int t = 0; t < 4; t++){
        a0 += __uint_as_float(v[t].x << 16);
        a1 += __uint_as_float(v[t].x & 0xFFFF0000u);
        a2 += __uint_as_float(v[t].y << 16);
        a3 += __uint_as_float(v[t].y & 0xFFFF0000u);
      }
    }
  }
  a0 += __shfl_xor(a0, 32);
  a1 += __shfl_xor(a1, 32);
  a2 += __shfl_xor(a2, 32);
  a3 += __shfl_xor(a3, 32);
  float o0 = fmaxf(a0*inv + __uint_as_float(sv.x << 16),          0.f);
  float o1 = fmaxf(a1*inv + __uint_as_float(sv.x & 0xFFFF0000u),  0.f);
  float o2 = fmaxf(a2*inv + __uint_as_float(sv.y << 16),          0.f);
  float o3 = fmaxf(a3*inv + __uint_as_float(sv.y & 0xFFFF0000u),  0.f);
  if constexpr (OUT_BF16){
    if (half == 0){   // H stays in permuted storage order
      uint2 pk;
      pk.x = ((unsigned)f2bf(o1) << 16) | (unsigned)f2bf(o0);
      pk.y = ((unsigned)f2bf(o3) << 16) | (unsigned)f2bf(o2);
      *(uint2*)((unsigned short*)OutV + (size_t)node*FDIM + L*4) = pk;
    }
  } else {
    // final output: un-permute. stored s = L*4+e -> orig c = (e+4*hi)*16 + n
    float* Out = (float*)OutV;
    int nn = L & 15, hi = L >> 4;
    float e0v = half ? o2 : o0;
    float e1v = half ? o3 : o1;
    int e0 = 2*half, e1 = 2*half + 1;
    Out[(size_t)node*FDIM + (e0 + 4*hi)*16 + nn] = e0v;
    Out[(size_t)node*FDIM + (e1 + 4*hi)*16 + nn] = e1v;
  }
}

extern "C" void kernel_launch(void* const* d_in, const int* in_sizes, int n_in,
                              void* d_out, int out_size, void* d_ws, size_t ws_size,
                              hipStream_t stream){
  const float* x   = (const float*)d_in[0];
  const int*   eix = (const int*)d_in[1];
  const float* Wl0 = (const float*)d_in[2];
  const float* bl0 = (const float*)d_in[3];
  const float* Wr0 = (const float*)d_in[4];
  const float* br0 = (const float*)d_in[5];
  const float* Wl1 = (const float*)d_in[6];
  const float* bl1 = (const float*)d_in[7];
  const float* Wr1 = (const float*)d_in[8];
  const float* br1 = (const float*)d_in[9];
  float* out = (float*)d_out;

  int N = in_sizes[0] / FDIM;
  int E = in_sizes[1] / 2;
  const int* src = eix;
  const int* dst = eix + E;

  // workspace layout (Z has N+1 rows: row N is the zero dummy row)
  unsigned short* Z    = (unsigned short*)d_ws;
  unsigned short* S    = Z + (size_t)(N + 1)*FDIM;
  unsigned short* Wcat = S + (size_t)N*FDIM;
  int*   cnt     = (int*)(Wcat + 2*256*128);
  int*   row_off = cnt + N;
  int*   cursor  = row_off + N;
  int*   csr_src = cursor + N;                 // capacity: E + 7N (padding bound)
  int*   partials= csr_src + (E + 7*N);

  unsigned short* H = (unsigned short*)d_out;  // layer-1 hidden, bf16, permuted

  int nb = (N + 255)/256;

  hipMemsetAsync(cnt, 0, (size_t)N*sizeof(int), stream);
  hipMemsetAsync(Z + (size_t)N*FDIM, 0, FDIM*sizeof(unsigned short), stream); // zero dummy row
  k_degree       <<<(E + 255)/256, 256, 0, stream>>>(dst, cnt, E);
  k_scan_blocks  <<<nb, 256, 0, stream>>>(cnt, row_off, partials, N);
  k_scan_partials<<<1, 512, 0, stream>>>(partials, nb);
  k_finalize     <<<nb, 256, 0, stream>>>(row_off, partials, cursor, N);
  k_fill         <<<(E + 255)/256, 256, 0, stream>>>(src, dst, cursor, csr_src, E);
  k_pad          <<<nb, 256, 0, stream>>>(cnt, row_off, csr_src, N);
  k_wcat         <<<(2*256*128 + 255)/256, 256, 0, stream>>>(Wl0, Wr0, Wl1, Wr1, Wcat);

  int nrb = (N + 63)/64;
  // layer 1: x (fp32) -> Z,S -> h (bf16, permuted, in d_out)
  k_dualgemm<false> <<<nrb, 256, 0, stream>>>(x, Wcat, bl0, br0, Z, S, N, nrb);
  k_aggregate<true> <<<(N + 3)/4, 256, 0, stream>>>(Z, S, row_off, cnt, csr_src, H, N);
  // layer 2: h (bf16) -> Z,S -> out (fp32, un-permuted)
  k_dualgemm<true>  <<<nrb, 256, 0, stream>>>(H, Wcat + 256*128, bl1, br1, Z, S, N, nrb);
  k_aggregate<false><<<(N + 3)/4, 256, 0, stream>>>(Z, S, row_off, cnt, csr_src, out, N);
}

// Round 5
// 288.693 us; speedup vs baseline: 1.2677x; 1.2677x over previous
//
#include <hip/hip_runtime.h>

#define FDIM 128

typedef __attribute__((ext_vector_type(8))) short bf16x8;
typedef __attribute__((ext_vector_type(4))) float f32x4;

// Column permutation for internal Z/S/H storage (within a 128-col half):
//   orig c: ct=c>>4, n=c&15  ->  stored s = 64*(ct>=4) + n*4 + (ct&3)
//   inv:    hi=s>>6, s6=s&63, n=s6>>2, ctl=s6&3 -> c = (ctl+4*hi)*16 + n
// Each lane's 4 ctl accumulators are contiguous in storage (8B packed stores
// in the GEMM epilogue, dwordx2 gathers in aggregate).

__device__ __forceinline__ unsigned short f2bf(float f){
  unsigned int u = __float_as_uint(f);
  unsigned int r = u + 0x7FFFu + ((u >> 16) & 1u);
  return (unsigned short)(r >> 16);
}

// ---------------- CSR build (padded to multiple of 8 per row) ----------------
__global__ void k_degree(const int* __restrict__ dst, int* __restrict__ cnt, int E){
  int e = blockIdx.x*256 + threadIdx.x;
  if (e < E) atomicAdd(&cnt[dst[e]], 1);
}

__global__ void k_scan_blocks(const int* __restrict__ cnt, int* __restrict__ excl,
                              int* __restrict__ partials, int N){
  __shared__ int s[256];
  int tid = threadIdx.x;
  int i = blockIdx.x*256 + tid;
  int v = (i < N) ? ((cnt[i] + 7) & ~7) : 0;   // scan PADDED degrees
  s[tid] = v; __syncthreads();
  for (int off = 1; off < 256; off <<= 1){
    int t = (tid >= off) ? s[tid - off] : 0;
    __syncthreads();
    s[tid] += t;
    __syncthreads();
  }
  if (i < N) excl[i] = s[tid] - v;
  if (tid == 255) partials[blockIdx.x] = s[255];
}

__global__ void k_scan_partials(int* __restrict__ partials, int nb){
  __shared__ int s[512];
  int tid = threadIdx.x;
  int v = (tid < nb) ? partials[tid] : 0;
  s[tid] = v; __syncthreads();
  for (int off = 1; off < 512; off <<= 1){
    int t = (tid >= off) ? s[tid - off] : 0;
    __syncthreads();
    s[tid] += t;
    __syncthreads();
  }
  if (tid < nb) partials[tid] = s[tid] - v;
}

__global__ void k_finalize(int* __restrict__ row_off, const int* __restrict__ partials,
                           int* __restrict__ cursor, int N){
  int i = blockIdx.x*256 + threadIdx.x;
  if (i >= N) return;
  int ro = row_off[i] + partials[blockIdx.x];
  row_off[i] = ro;
  cursor[i]  = ro;
}

__global__ void k_fill(const int* __restrict__ src, const int* __restrict__ dst,
                       int* __restrict__ cursor, int* __restrict__ csr_src, int E){
  int e = blockIdx.x*256 + threadIdx.x;
  if (e >= E) return;
  int d = dst[e];
  int pos = atomicAdd(&cursor[d], 1);
  csr_src[pos] = src[e];
}

// fill padding slots with dummy node index N (Z row N is zeroed)
__global__ void k_pad(const int* __restrict__ cnt, const int* __restrict__ row_off,
                      int* __restrict__ csr_src, int N){
  int i = blockIdx.x*256 + threadIdx.x;
  if (i >= N) return;
  int d  = cnt[i];
  int pd = (d + 7) & ~7;
  int ro = row_off[i];
  for (int p = d; p < pd; p++) csr_src[ro + p] = N;
}

// ---------------- weight pre-convert: Wcat[layer][256][128] bf16 ----------------
// Layer-2 weights get inverse-permuted k (their A input, H, is stored permuted).
__global__ void k_wcat(const float* __restrict__ Wl0, const float* __restrict__ Wr0,
                       const float* __restrict__ Wl1, const float* __restrict__ Wr1,
                       unsigned short* __restrict__ Wcat){
  int i = blockIdx.x*256 + threadIdx.x;
  if (i >= 2*256*128) return;
  int l   = i >> 15;
  int rem = i & 32767;
  int row = rem >> 7, k = rem & 127;
  int ksrc = k;
  if (l == 1){
    int hi = k >> 6, s6 = k & 63;
    ksrc = ((s6 & 3) + 4*hi)*16 + (s6 >> 2);   // invπ(k)
  }
  const float* W = (l == 0) ? ((row < 128) ? Wl0 : Wr0)
                            : ((row < 128) ? Wl1 : Wr1);
  Wcat[i] = f2bf(W[(row & 127)*128 + ksrc]);
}

// ---------------- dual GEMM: Z = X@Wl^T, S = X@Wr^T + (bl+br), permuted cols ----------------
// Software-pipelined: next tile's X is loaded into registers during the current
// tile's MFMA+epilogue. launch_bounds(256,2): cap 256 VGPR, NO spills (R4 lesson:
// (256,4) forced VGPR<=64 -> acc spilled to scratch -> 3x write traffic).
template<bool A_BF16>
__global__ __launch_bounds__(256, 2)
void k_dualgemm(const void* __restrict__ Xv, const unsigned short* __restrict__ Wcat,
                const float* __restrict__ bl, const float* __restrict__ br,
                unsigned short* __restrict__ Z, unsigned short* __restrict__ S,
                int N, int nrb){
  __shared__ unsigned short lds[64*FDIM]; // 16 KiB
  const int tid  = threadIdx.x;
  const int wave = tid >> 6;
  const int lane = tid & 63;
  const int n = lane & 15, q = lane >> 4;

  float bias[4];
#pragma unroll
  for (int ctl = 0; ctl < 4; ctl++){
    int ct = wave*4 + ctl;
    if (ct >= 8){ int col = (ct - 8)*16 + n; bias[ctl] = bl[col] + br[col]; }
    else bias[ctl] = 0.0f;
  }

  // prefetch registers (one tile's worth per thread)
  float4 pf[8];   // fp32 path: 8 x float4 = 32B x 4 its
  bf16x8 pb[4];   // bf16 path: 4 x 16B

  const int r_   = tid >> 4;          // staging row this thread covers (per it: +64)
  const int c16_ = tid & 15;          // staging 16B-chunk

  auto issue_load = [&](int rb){
    int row0 = rb*64;
#pragma unroll
    for (int it = 0; it < 4; it++){
      int r  = r_ + it*16;
      int gr = row0 + r;
      if constexpr (A_BF16){
        const unsigned short* X = (const unsigned short*)Xv;
        if (gr < N) pb[it] = *(const bf16x8*)(X + (size_t)gr*FDIM + c16_*8);
        else { bf16x8 zz; 
#pragma unroll
               for (int z = 0; z < 8; z++) zz[z] = 0; pb[it] = zz; }
      } else {
        const float* X = (const float*)Xv;
        if (gr < N){
          const float4* sp = (const float4*)(X + (size_t)gr*FDIM + c16_*8);
          pf[2*it]   = sp[0];
          pf[2*it+1] = sp[1];
        } else {
          pf[2*it]   = make_float4(0,0,0,0);
          pf[2*it+1] = make_float4(0,0,0,0);
        }
      }
    }
  };

  int rb = blockIdx.x;
  if (rb < nrb) issue_load(rb);

  for (; rb < nrb; rb += gridDim.x){
    int row0 = rb*64;
    __syncthreads();   // previous tile's LDS readers done
    // write prefetched tile -> LDS (convert if fp32), swizzled chunk
#pragma unroll
    for (int it = 0; it < 4; it++){
      int r = r_ + it*16;
      bf16x8 p;
      if constexpr (A_BF16){
        p = pb[it];
      } else {
        float4 v0 = pf[2*it], v1 = pf[2*it+1];
        p[0] = (short)f2bf(v0.x); p[1] = (short)f2bf(v0.y);
        p[2] = (short)f2bf(v0.z); p[3] = (short)f2bf(v0.w);
        p[4] = (short)f2bf(v1.x); p[5] = (short)f2bf(v1.y);
        p[6] = (short)f2bf(v1.z); p[7] = (short)f2bf(v1.w);
      }
      *(bf16x8*)(lds + r*FDIM + ((c16_ ^ (r & 15)) * 8)) = p;
    }
    __syncthreads();

    // issue next tile's global loads NOW; they complete during MFMA+epilogue
    int rbn = rb + gridDim.x;
    if (rbn < nrb) issue_load(rbn);

    f32x4 acc[4][4];
#pragma unroll
    for (int rt = 0; rt < 4; rt++)
#pragma unroll
      for (int ctl = 0; ctl < 4; ctl++)
        acc[rt][ctl] = (f32x4){0.f, 0.f, 0.f, 0.f};

#pragma unroll
    for (int kk = 0; kk < 4; kk++){
      bf16x8 bfr[4];
#pragma unroll
      for (int ctl = 0; ctl < 4; ctl++){
        int row = (wave*4 + ctl)*16 + n;
        bfr[ctl] = *(const bf16x8*)(Wcat + row*FDIM + kk*32 + q*8);
      }
      bf16x8 afr[4];
#pragma unroll
      for (int rt = 0; rt < 4; rt++){
        int r = rt*16 + n;
        int c16 = (kk*4 + q) ^ n;
        afr[rt] = *(const bf16x8*)(lds + r*FDIM + c16*8);
      }
#pragma unroll
      for (int rt = 0; rt < 4; rt++)
#pragma unroll
        for (int ctl = 0; ctl < 4; ctl++)
          acc[rt][ctl] = __builtin_amdgcn_mfma_f32_16x16x32_bf16(
              afr[rt], bfr[ctl], acc[rt][ctl], 0, 0, 0);
    }

    // epilogue: wave<2 -> Z half, wave>=2 -> S half; packed 8B stores.
    unsigned short* dstb = (wave < 2) ? Z : S;
    int s0 = 64*(wave & 1) + n*4;
#pragma unroll
    for (int rt = 0; rt < 4; rt++){
#pragma unroll
      for (int r = 0; r < 4; r++){
        int grow = row0 + rt*16 + q*4 + r;
        if (grow < N){
          float v0 = acc[rt][0][r] + bias[0];
          float v1 = acc[rt][1][r] + bias[1];
          float v2 = acc[rt][2][r] + bias[2];
          float v3 = acc[rt][3][r] + bias[3];
          uint2 u;
          u.x = ((unsigned)f2bf(v1) << 16) | (unsigned)f2bf(v0);
          u.y = ((unsigned)f2bf(v3) << 16) | (unsigned)f2bf(v2);
          *(uint2*)(dstb + (size_t)grow*FDIM + s0) = u;
        }
      }
    }
  }
}

// ---------------- aggregate + finish: out = relu(sum(Z[src])/deg + S) ----------------
// One wave per node. Padded CSR (multiple of 8, dummy -> zero row N of Z).
// dwordx2 gathers: half-wave covers a row (4 stored cols/lane), two edges per
// gather batch slot; xor-32 combine at the end. No masks in the inner loop.
template<bool OUT_BF16>
__global__ __launch_bounds__(256)
void k_aggregate(const unsigned short* __restrict__ Z, const unsigned short* __restrict__ S,
                 const int* __restrict__ row_off, const int* __restrict__ cnt,
                 const int* __restrict__ csr_src, void* __restrict__ OutV, int N){
  int wave = threadIdx.x >> 6, lane = threadIdx.x & 63;
  int node = blockIdx.x*4 + wave;
  if (node >= N) return;
  int start = row_off[node];
  int deg   = cnt[node];
  int pdeg  = (deg + 7) & ~7;
  float inv = 1.0f / (float)(deg > 1 ? deg : 1);
  int L = lane & 31, half = lane >> 5;
  uint2 sv = *(const uint2*)(S + (size_t)node*FDIM + L*4);

  const int* cb = csr_src + start;
  float a0 = 0.f, a1 = 0.f, a2 = 0.f, a3 = 0.f;
  for (int base = 0; base < pdeg; base += 64){
    int m = pdeg - base; if (m > 64) m = 64;      // multiple of 8
    int sidx = (lane < m) ? cb[base + lane] : N;
    for (int j = 0; j < m; j += 8){
      int id[4];
#pragma unroll
      for (int t = 0; t < 4; t++)
        id[t] = __shfl(sidx, j + 2*t + half);     // 4 bpermutes / 8 edges
      uint2 v[4];
#pragma unroll
      for (int t = 0; t < 4; t++){
        unsigned u = (unsigned)id[t];
        if (u > (unsigned)N) u = (unsigned)N;     // defensive clamp (row N = zeros)
        v[t] = *(const uint2*)(Z + (size_t)u*FDIM + L*4);
      }
#pragma unroll
      for (int t = 0; t < 4; t++){
        a0 += __uint_as_float(v[t].x << 16);
        a1 += __uint_as_float(v[t].x & 0xFFFF0000u);
        a2 += __uint_as_float(v[t].y << 16);
        a3 += __uint_as_float(v[t].y & 0xFFFF0000u);
      }
    }
  }
  a0 += __shfl_xor(a0, 32);
  a1 += __shfl_xor(a1, 32);
  a2 += __shfl_xor(a2, 32);
  a3 += __shfl_xor(a3, 32);
  float o0 = fmaxf(a0*inv + __uint_as_float(sv.x << 16),          0.f);
  float o1 = fmaxf(a1*inv + __uint_as_float(sv.x & 0xFFFF0000u),  0.f);
  float o2 = fmaxf(a2*inv + __uint_as_float(sv.y << 16),          0.f);
  float o3 = fmaxf(a3*inv + __uint_as_float(sv.y & 0xFFFF0000u),  0.f);
  if constexpr (OUT_BF16){
    if (half == 0){   // H stays in permuted storage order
      uint2 pk;
      pk.x = ((unsigned)f2bf(o1) << 16) | (unsigned)f2bf(o0);
      pk.y = ((unsigned)f2bf(o3) << 16) | (unsigned)f2bf(o2);
      *(uint2*)((unsigned short*)OutV + (size_t)node*FDIM + L*4) = pk;
    }
  } else {
    // final output: un-permute. stored s = L*4+e -> orig c = (e+4*hi)*16 + nn
    float* Out = (float*)OutV;
    int nn = L & 15, hi = L >> 4;
    float e0v = half ? o2 : o0;
    float e1v = half ? o3 : o1;
    int e0 = 2*half, e1 = 2*half + 1;
    Out[(size_t)node*FDIM + (e0 + 4*hi)*16 + nn] = e0v;
    Out[(size_t)node*FDIM + (e1 + 4*hi)*16 + nn] = e1v;
  }
}

extern "C" void kernel_launch(void* const* d_in, const int* in_sizes, int n_in,
                              void* d_out, int out_size, void* d_ws, size_t ws_size,
                              hipStream_t stream){
  const float* x   = (const float*)d_in[0];
  const int*   eix = (const int*)d_in[1];
  const float* Wl0 = (const float*)d_in[2];
  const float* bl0 = (const float*)d_in[3];
  const float* Wr0 = (const float*)d_in[4];
  const float* br0 = (const float*)d_in[5];
  const float* Wl1 = (const float*)d_in[6];
  const float* bl1 = (const float*)d_in[7];
  const float* Wr1 = (const float*)d_in[8];
  const float* br1 = (const float*)d_in[9];
  float* out = (float*)d_out;

  int N = in_sizes[0] / FDIM;
  int E = in_sizes[1] / 2;
  const int* src = eix;
  const int* dst = eix + E;

  // workspace layout (Z has N+1 rows: row N is the zero dummy row)
  unsigned short* Z    = (unsigned short*)d_ws;
  unsigned short* S    = Z + (size_t)(N + 1)*FDIM;
  unsigned short* Wcat = S + (size_t)N*FDIM;
  int*   cnt     = (int*)(Wcat + 2*256*128);
  int*   row_off = cnt + N;
  int*   cursor  = row_off + N;
  int*   csr_src = cursor + N;                 // capacity: E + 7N (padding bound)
  int*   partials= csr_src + (E + 7*N);

  unsigned short* H = (unsigned short*)d_out;  // layer-1 hidden, bf16, permuted

  int nb = (N + 255)/256;

  hipMemsetAsync(cnt, 0, (size_t)N*sizeof(int), stream);
  hipMemsetAsync(Z + (size_t)N*FDIM, 0, FDIM*sizeof(unsigned short), stream); // zero dummy row
  k_degree       <<<(E + 255)/256, 256, 0, stream>>>(dst, cnt, E);
  k_scan_blocks  <<<nb, 256, 0, stream>>>(cnt, row_off, partials, N);
  k_scan_partials<<<1, 512, 0, stream>>>(partials, nb);
  k_finalize     <<<nb, 256, 0, stream>>>(row_off, partials, cursor, N);
  k_fill         <<<(E + 255)/256, 256, 0, stream>>>(src, dst, cursor, csr_src, E);
  k_pad          <<<nb, 256, 0, stream>>>(cnt, row_off, csr_src, N);
  k_wcat         <<<(2*256*128 + 255)/256, 256, 0, stream>>>(Wl0, Wr0, Wl1, Wr1, Wcat);

  int nrb = (N + 63)/64;
  // layer 1: x (fp32) -> Z,S -> h (bf16, permuted, in d_out)
  k_dualgemm<false> <<<512, 256, 0, stream>>>(x, Wcat, bl0, br0, Z, S, N, nrb);
  k_aggregate<true> <<<(N + 3)/4, 256, 0, stream>>>(Z, S, row_off, cnt, csr_src, H, N);
  // layer 2: h (bf16) -> Z,S -> out (fp32, un-permuted)
  k_dualgemm<true>  <<<512, 256, 0, stream>>>(H, Wcat + 256*128, bl1, br1, Z, S, N, nrb);
  k_aggregate<false><<<(N + 3)/4, 256, 0, stream>>>(Z, S, row_off, cnt, csr_src, out, N);
}